// Round 12
// baseline (56.808 us; speedup 1.0000x reference)
//
#include <hip/hip_runtime.h>
#include <hip/hip_bf16.h>

// Problem dims (fixed by reference): B=64 S=256 F=4 V=50257 H=768 D=512
#define M_TOT 16384   // B*S
#define K_TOT 768     // H
#define N_TOT 512     // D
#define NT 12         // K-chunks of 64

typedef __attribute__((ext_vector_type(8))) __bf16 bf16x8;
typedef __attribute__((ext_vector_type(4))) float f32x4;

static __device__ __forceinline__ ushort f2bf(float x) {
  union { float f; unsigned int u; } v; v.f = x;
  unsigned int r = v.u + 0x7fffu + ((v.u >> 16) & 1u);
  return (ushort)(r >> 16);
}
static __device__ __forceinline__ unsigned pack2(float lo, float hi) {
  return (unsigned)f2bf(lo) | ((unsigned)f2bf(hi) << 16);
}

// ---------------------------------------------------------------------------
// Kernel 1: W[768][512] f32 -> Wt_frag bf16 fragment-major:
//   W[k][col] -> Wt[ ((k>>3)*512 + col)*8 + (k&7) ]
// ---------------------------------------------------------------------------
__global__ __launch_bounds__(256) void wt_kernel(const float* __restrict__ W,
                                                 ushort* __restrict__ Wt) {
  __shared__ float tile[64][65];
  const int t  = threadIdx.x;
  const int k0 = blockIdx.x * 64;
  const int n0 = blockIdx.y * 64;
#pragma unroll
  for (int i = 0; i < 4; ++i) {
    const int idx = t + i * 256;
    const int r = idx >> 4;
    const int c = (idx & 15) * 4;
    const float4 v =
        *reinterpret_cast<const float4*>(W + (size_t)(k0 + r) * N_TOT + n0 + c);
    tile[r][c + 0] = v.x; tile[r][c + 1] = v.y;
    tile[r][c + 2] = v.z; tile[r][c + 3] = v.w;
  }
  __syncthreads();
#pragma unroll
  for (int i = 0; i < 4; ++i) {
    const int idx = t + i * 256;
    const int rn = idx >> 4;        // col within tile
    const int ck = (idx & 15) * 4;  // k within tile
    ushort4 o;
    o.x = f2bf(tile[ck + 0][rn]);
    o.y = f2bf(tile[ck + 1][rn]);
    o.z = f2bf(tile[ck + 2][rn]);
    o.w = f2bf(tile[ck + 3][rn]);
    const int kg    = k0 + ck;
    const int chunk = kg >> 3;
    const int e0    = kg & 7;
    *reinterpret_cast<ushort4*>(
        &Wt[((size_t)chunk * N_TOT + n0 + rn) * 8 + e0]) = o;
  }
}

// ---------------------------------------------------------------------------
// Kernel 2 (FUSED, vmcnt-aware pipeline): out = mean-gather(E,words)@W + bias.
// 256 blocks (1/CU) x 512 threads (8 waves). BM=64 as two 32-row sub-tiles.
//   gather(S0) | bar | GEMM(S0) + S1 E-prefetch in 2 fenced batches | bar |
//   GEMM(S1)
// KEY (R7/R8/R9 post-mortem): vmcnt retires IN ORDER. E loads (HBM ~900cy)
// issued BEFORE B-fragment loads (L2 ~200cy) poison every subsequent B wait.
// Here each E batch is issued AFTER a run of B loads and consumed (G_MATH)
// ~6 substeps (~1400cy) later: one ~900cy bubble per batch, everything else
// flows. sched_barrier(0) pins the issue order.
// ---------------------------------------------------------------------------
__global__ __launch_bounds__(512, 1) void fused_kernel(
    const int* __restrict__ words, const float* __restrict__ E,
    const ushort* __restrict__ Wt, const float* __restrict__ bias,
    float* __restrict__ out) {
  __shared__ ushort A0[32 * 96 * 8];  // 48 KB  [lrow][slot][8]
  __shared__ ushort A1[32 * 96 * 8];  // 48 KB
  __shared__ int   eoff_l[64][4];
  __shared__ float msk_l[64][4];
  __shared__ float scl_l[64];

  const int t    = threadIdx.x;
  const int lane = t & 63;
  const int w    = t >> 6;   // 0..7
  const int bm   = blockIdx.x;
  const int w4   = w * 4;    // wave's 4-row base within a sub-tile

  // ---- metadata for all 64 rows ----
  if (t < 64) {
    const int4 wd =
        *reinterpret_cast<const int4*>(words + (size_t)(bm * 64 + t) * 4);
    const int ids[4] = {wd.x, wd.y, wd.z, wd.w};
    float cnt = 0.f;
#pragma unroll
    for (int f = 0; f < 4; ++f) {
      eoff_l[t][f] = ids[f] * K_TOT;
      const float m = (ids[f] != 0) ? 1.f : 0.f;
      msk_l[t][f] = m;
      cnt += m;
    }
    scl_l[t] = (cnt > 0.f) ? (1.f / cnt) : 0.f;
  }
  __syncthreads();

  float4 vA[12], vB[12];  // two in-flight rows (static names, rule #20)

  // contiguous-row load: lane covers float4 [lane],[64+lane],[128+lane] per id
#define G_LOAD(vv, grow)                                                     \
  do {                                                                       \
    const int row_ = (grow);                                                 \
    _Pragma("unroll") for (int f = 0; f < 4; ++f) {                          \
      const float4* p_ =                                                     \
          reinterpret_cast<const float4*>(E + eoff_l[row_][f]) + lane;       \
      vv[f * 3 + 0] = p_[0];                                                 \
      vv[f * 3 + 1] = p_[64];                                                \
      vv[f * 3 + 2] = p_[128];                                               \
    }                                                                        \
  } while (0)

#define G_MATH(vv, grow, dstA, lrow)                                         \
  do {                                                                       \
    const int row_ = (grow);                                                 \
    const float km0 = msk_l[row_][0], km1 = msk_l[row_][1];                  \
    const float km2 = msk_l[row_][2], km3 = msk_l[row_][3];                  \
    const float ksc = scl_l[row_];                                           \
    _Pragma("unroll") for (int c = 0; c < 3; ++c) {                          \
      float s[4];                                                            \
      _Pragma("unroll") for (int j = 0; j < 4; ++j)                          \
        s[j] = (vv[0 * 3 + c][j] * km0 + vv[1 * 3 + c][j] * km1 +            \
                vv[2 * 3 + c][j] * km2 + vv[3 * 3 + c][j] * km3) * ksc;      \
      uint2 o_;                                                              \
      o_.x = pack2(s[0], s[1]);                                              \
      o_.y = pack2(s[2], s[3]);                                              \
      const int slot_ = c * 32 + ((lane >> 1) ^ (row_ & 7));                 \
      *reinterpret_cast<uint2*>(                                             \
          &(dstA)[(lrow) * 768 + slot_ * 8 + (lane & 1) * 4]) = o_;          \
    }                                                                        \
  } while (0)

  // ---- GEMM per-wave params: 32 rows x cols [w*64, +64), acc 2x4 ----
  const int rsel = lane & 15;
  const int ksel = lane >> 4;
  const int colBase = w * 64 + rsel;
  f32x4 acc[2][4];

#define COMPUTE(Asrc, kt)                                                    \
  do {                                                                       \
    _Pragma("unroll") for (int kk = 0; kk < 2; ++kk) {                       \
      const int g = (kt) * 8 + kk * 4 + ksel;                                \
      bf16x8 af[2], bfr[4];                                                  \
      _Pragma("unroll") for (int m = 0; m < 2; ++m) {                        \
        const int r_ = m * 16 + rsel;                                        \
        af[m] = *reinterpret_cast<const bf16x8*>(                            \
            &(Asrc)[r_ * 768 + ((g ^ (r_ & 7))) * 8]);                       \
      }                                                                      \
      _Pragma("unroll") for (int n = 0; n < 4; ++n)                          \
        bfr[n] = *reinterpret_cast<const bf16x8*>(                           \
            &Wt[((size_t)g * N_TOT + colBase + n * 16) * 8]);                \
      __builtin_amdgcn_s_setprio(1);                                         \
      _Pragma("unroll") for (int m = 0; m < 2; ++m)                          \
        _Pragma("unroll") for (int n = 0; n < 4; ++n)                        \
          acc[m][n] = __builtin_amdgcn_mfma_f32_16x16x32_bf16(               \
              af[m], bfr[n], acc[m][n], 0, 0, 0);                            \
      __builtin_amdgcn_s_setprio(0);                                         \
    }                                                                        \
  } while (0)

#define EPILOGUE(T)                                                          \
  do {                                                                       \
    const int row0 = bm * 64 + (T) * 32 + (ksel << 2);                       \
    _Pragma("unroll") for (int n = 0; n < 4; ++n) {                          \
      const float bv = bias[colBase + n * 16];                               \
      _Pragma("unroll") for (int m = 0; m < 2; ++m) {                        \
        _Pragma("unroll") for (int j = 0; j < 4; ++j) {                      \
          __builtin_nontemporal_store(                                       \
              acc[m][n][j] + bv,                                             \
              &out[(size_t)(row0 + m * 16 + j) * N_TOT + colBase + n * 16]); \
        }                                                                    \
      }                                                                      \
    }                                                                        \
  } while (0)

  // ================= gather S0 (rows w4..w4+3) -> A0 =======================
  G_LOAD(vA, w4 + 0);
  G_LOAD(vB, w4 + 1);
  G_MATH(vA, w4 + 0, A0, w4 + 0);  G_LOAD(vA, w4 + 2);
  G_MATH(vB, w4 + 1, A0, w4 + 1);  G_LOAD(vB, w4 + 3);
  G_MATH(vA, w4 + 2, A0, w4 + 2);
  G_MATH(vB, w4 + 3, A0, w4 + 3);
  __syncthreads();  // A0 ready

  // ================= GEMM(S0) + S1 prefetch in 2 fenced batches ============
#pragma unroll
  for (int m = 0; m < 2; ++m)
#pragma unroll
    for (int n = 0; n < 4; ++n) acc[m][n] = (f32x4){0.f, 0.f, 0.f, 0.f};

  __builtin_amdgcn_sched_barrier(0);
  G_LOAD(vA, 32 + w4 + 0);           // batch 1 issue (HBM, flies under GEMM)
  G_LOAD(vB, 32 + w4 + 1);
  __builtin_amdgcn_sched_barrier(0);
  COMPUTE(A0, 0);  COMPUTE(A0, 1);  COMPUTE(A0, 2);
  COMPUTE(A0, 3);  COMPUTE(A0, 4);  COMPUTE(A0, 5);
  G_MATH(vA, 32 + w4 + 0, A1, w4 + 0);  // batch 1 retired ~1400cy ago
  G_MATH(vB, 32 + w4 + 1, A1, w4 + 1);
  __builtin_amdgcn_sched_barrier(0);
  G_LOAD(vA, 32 + w4 + 2);           // batch 2 issue
  G_LOAD(vB, 32 + w4 + 3);
  __builtin_amdgcn_sched_barrier(0);
  COMPUTE(A0, 6);  COMPUTE(A0, 7);  COMPUTE(A0, 8);
  COMPUTE(A0, 9);  COMPUTE(A0, 10); COMPUTE(A0, 11);
  G_MATH(vA, 32 + w4 + 2, A1, w4 + 2);
  G_MATH(vB, 32 + w4 + 3, A1, w4 + 3);
  EPILOGUE(0);
  __syncthreads();  // A1 ready

  // ================= GEMM(S1) ==============================================
#pragma unroll
  for (int m = 0; m < 2; ++m)
#pragma unroll
    for (int n = 0; n < 4; ++n) acc[m][n] = (f32x4){0.f, 0.f, 0.f, 0.f};
#pragma unroll
  for (int kt = 0; kt < NT; ++kt) COMPUTE(A1, kt);
  EPILOGUE(1);

#undef G_LOAD
#undef G_MATH
#undef COMPUTE
#undef EPILOGUE
}

// ---------------------------------------------------------------------------
extern "C" void kernel_launch(void* const* d_in, const int* in_sizes, int n_in,
                              void* d_out, int out_size, void* d_ws,
                              size_t ws_size, hipStream_t stream) {
  const int*   words = (const int*)d_in[0];
  const float* E     = (const float*)d_in[1];
  const float* W     = (const float*)d_in[2];
  const float* b     = (const float*)d_in[3];
  float* out = (float*)d_out;

  ushort* Wtws = (ushort*)d_ws;  // 512*768 bf16, fragment-major

  hipLaunchKernelGGL(wt_kernel, dim3(K_TOT / 64, N_TOT / 64), dim3(256), 0,
                     stream, W, Wtws);
  hipLaunchKernelGGL(fused_kernel, dim3(M_TOT / 64), dim3(512), 0, stream,
                     words, E, Wtws, b, out);
}